// Round 5
// baseline (991.289 us; speedup 1.0000x reference)
//
#include <hip/hip_runtime.h>
#include <stdint.h>

typedef __attribute__((ext_vector_type(4))) float  floatx4;
typedef __attribute__((ext_vector_type(8))) short  short8;
typedef __attribute__((ext_vector_type(8))) __bf16 bf16x8;

__device__ __forceinline__ unsigned short f2bf(float f) {
  unsigned int u = __builtin_bit_cast(unsigned int, f);
  u += 0x7fffu + ((u >> 16) & 1u);   // round-to-nearest-even
  return (unsigned short)(u >> 16);
}

typedef const __attribute__((address_space(1))) void* gptr_t;
typedef __attribute__((address_space(3))) void*       lptr_t;

// ---------------- fused prep: cast_x | transpose_v | prep_u ----------------
__global__ __launch_bounds__(256) void prep_fused(
    const float* __restrict__ X, const float* __restrict__ V,
    const float* __restrict__ U, const float* __restrict__ S,
    unsigned short* __restrict__ Xb, unsigned short* __restrict__ Vt,
    unsigned short* __restrict__ Ub,
    int castBlocks, int transTotal, int transGX, int vrows, int vcols,
    unsigned int rankMask) {
  __shared__ float tile[32][33];
  int bid = blockIdx.x;
  int tid = threadIdx.x;
  if (bid < castBlocks) {
    size_t i = ((size_t)bid * 256 + tid) * 8;
    const floatx4* p = (const floatx4*)(X + i);
    floatx4 a = p[0], b = p[1];
    union { unsigned short us[8]; short8 v; } o;
    o.us[0] = f2bf(a[0]); o.us[1] = f2bf(a[1]); o.us[2] = f2bf(a[2]); o.us[3] = f2bf(a[3]);
    o.us[4] = f2bf(b[0]); o.us[5] = f2bf(b[1]); o.us[6] = f2bf(b[2]); o.us[7] = f2bf(b[3]);
    *(short8*)(Xb + i) = o.v;
  } else if (bid < castBlocks + transTotal) {
    int b  = bid - castBlocks;
    int bx = (b % transGX) * 32;     // rank dim
    int by = (b / transGX) * 32;     // out_h dim
    int tx = tid & 31;
    int ty = tid >> 5;
    for (int i = ty; i < 32; i += 8)
      tile[i][tx] = V[(size_t)(by + i) * vcols + bx + tx];
    __syncthreads();
    // Vectorized store: one 8B (4x bf16) store per thread.
    // Vt[bx+i][by+c] = tile[c][i]; thread (g=tid&7, i2=tid>>3) covers c=g*4..+3.
    {
      int g = tid & 7, i2 = tid >> 3;
      union { unsigned short us[4]; unsigned long long v; } w;
#pragma unroll
      for (int j = 0; j < 4; ++j) w.us[j] = f2bf(tile[g * 4 + j][i2]);
      *(unsigned long long*)(Vt + (size_t)(bx + i2) * vrows + by + g * 4) = w.v;
    }
  } else {
    int b = bid - castBlocks - transTotal;
    size_t i = ((size_t)b * 256 + tid) * 4;
    floatx4 u = *(const floatx4*)(U + i);
    floatx4 s = *(const floatx4*)(S + (i & (size_t)rankMask));
    union { unsigned short us[4]; unsigned long long v; } o;
    o.us[0] = f2bf(u[0] * s[0]); o.us[1] = f2bf(u[1] * s[1]);
    o.us[2] = f2bf(u[2] * s[2]); o.us[3] = f2bf(u[3] * s[3]);
    *(unsigned long long*)(Ub + i) = o.v;
  }
}

// ---------------- GEMM1: Yb[M,N] bf16 = A[M,K] @ Bt[N,K]^T ----------------
// BM=128, BN=128, BK=64, 256 threads (4 waves 2x2, wave-tile 64x64 = 4x4 of
// 16x16x32). Counted-vmcnt double buffer (8 loads/tile/thread, steady-state
// vmcnt(8), vmcnt(0) only at tail), XOR slot-swizzle, raw s_barrier, setprio.
// (Verified round-4: ~68 us, 2 blocks/CU.)
__global__ __launch_bounds__(256, 2)
void gemm1_kernel(const unsigned short* __restrict__ A,
                  const unsigned short* __restrict__ Bt,
                  unsigned short* __restrict__ C,
                  int N, int K, int GX) {
  __shared__ unsigned short sA[2][128 * 64];   // 16 KiB per buf
  __shared__ unsigned short sB[2][128 * 64];

  const int tid  = threadIdx.x;
  const int lane = tid & 63;
  const int wave = tid >> 6;
  const int wm = (wave >> 1) * 64;
  const int wn = (wave & 1) * 64;

  unsigned bid  = blockIdx.x;
  unsigned bw   = 8u * GX;
  unsigned band = bid / bw, rem = bid % bw;
  unsigned by   = band * 8 + (rem & 7u);
  unsigned bx   = rem >> 3;
  const int row0 = by * 128, col0 = bx * 128;

  floatx4 acc[4][4];
#pragma unroll
  for (int i = 0; i < 4; ++i)
#pragma unroll
    for (int j = 0; j < 4; ++j) acc[i][j] = (floatx4){0.f, 0.f, 0.f, 0.f};

  // Staging: LDS dest linear (row = j*32 + wave*8 + lane/8, slot lane&7);
  // global source embeds inverse swizzle: slot = (lane&7) ^ (row&7),
  // row&7 == lane>>3 (wave*8 and j*32 are 0 mod 8).
  const int srow = wave * 8 + (lane >> 3);     // [0,32)
  const int ssl  = (lane & 7) ^ (lane >> 3);
  const unsigned short* Ag = A  + (size_t)(row0 + srow) * K + ssl * 8;
  const unsigned short* Bg = Bt + (size_t)(col0 + srow) * K + ssl * 8;
  const int ldsw = (wave * 8) * 64;            // wave-uniform ushort offset

  // Fragment reads: phys 16B slot = (ks*4+quad) ^ (row&7), row&7 == mrow&7.
  const int mrow = lane & 15, quad = lane >> 4;
  const int sw   = mrow & 7;
  const int pko0 = ((quad    ) ^ sw) << 3;     // ks=0, ushort offset
  const int pko1 = ((quad + 4) ^ sw) << 3;     // ks=1

  const int NKT = K >> 6;                      // 64 for K=4096

  // 8 global_load_lds per K-tile per thread (4 A + 4 B), 32 rows per j-step.
#define STAGE_G1(KOFF, BUF)                                                    \
  {                                                                            \
    const unsigned short* As_ = Ag + (KOFF);                                   \
    const unsigned short* Bs_ = Bg + (KOFF);                                   \
    unsigned short* dA_ = &sA[(BUF)][0] + ldsw;                                \
    unsigned short* dB_ = &sB[(BUF)][0] + ldsw;                                \
    _Pragma("unroll")                                                          \
    for (int j_ = 0; j_ < 4; ++j_) {                                           \
      __builtin_amdgcn_global_load_lds((gptr_t)(As_ + (size_t)j_ * 32 * K),    \
                                       (lptr_t)(dA_ + j_ * 2048), 16, 0, 0);   \
      __builtin_amdgcn_global_load_lds((gptr_t)(Bs_ + (size_t)j_ * 32 * K),    \
                                       (lptr_t)(dB_ + j_ * 2048), 16, 0, 0);   \
    }                                                                          \
  }

  // Prologue: T0 -> buf0, T1 -> buf1; wait T0 landed (T1's 8 stay in flight).
  STAGE_G1(0, 0);
  STAGE_G1(64, 1);
  asm volatile("s_waitcnt vmcnt(8)" ::: "memory");
  __builtin_amdgcn_s_barrier();

  int cur = 0;
  for (int kt = 0; kt < NKT; ++kt) {
    const unsigned short* bA = &sA[cur][0];
    const unsigned short* bB = &sB[cur][0];
#pragma unroll
    for (int ks = 0; ks < 2; ++ks) {
      const int pko = ks ? pko1 : pko0;
      bf16x8 bfr[4], af[4];
#pragma unroll
      for (int ni = 0; ni < 4; ++ni)
        bfr[ni] = __builtin_bit_cast(bf16x8,
                    *(const short8*)(bB + (wn + ni * 16 + mrow) * 64 + pko));
#pragma unroll
      for (int mi = 0; mi < 4; ++mi)
        af[mi] = __builtin_bit_cast(bf16x8,
                    *(const short8*)(bA + (wm + mi * 16 + mrow) * 64 + pko));
      __builtin_amdgcn_s_setprio(1);
#pragma unroll
      for (int mi = 0; mi < 4; ++mi)
#pragma unroll
        for (int ni = 0; ni < 4; ++ni)
          acc[mi][ni] = __builtin_amdgcn_mfma_f32_16x16x32_bf16(af[mi], bfr[ni],
                                                                acc[mi][ni], 0, 0, 0);
      __builtin_amdgcn_s_setprio(0);
    }
    // All reads of buf[cur] complete -> barrier -> safe to restage buf[cur].
    asm volatile("s_waitcnt lgkmcnt(0)" ::: "memory");
    __builtin_amdgcn_sched_barrier(0);
    __builtin_amdgcn_s_barrier();
    __builtin_amdgcn_sched_barrier(0);
    if (kt + 2 < NKT) {
      STAGE_G1((kt + 2) * 64, cur);
      // wait for T(kt+1)'s 8 loads; T(kt+2)'s 8 remain in flight
      asm volatile("s_waitcnt vmcnt(8)" ::: "memory");
      __builtin_amdgcn_s_barrier();
    } else if (kt + 1 < NKT) {
      asm volatile("s_waitcnt vmcnt(0)" ::: "memory");
      __builtin_amdgcn_s_barrier();
    }
    cur ^= 1;
  }
#undef STAGE_G1

  const int orow = row0 + wm + quad * 4;
  const int ocol = col0 + wn + mrow;
#pragma unroll
  for (int mi = 0; mi < 4; ++mi)
#pragma unroll
    for (int r = 0; r < 4; ++r) {
      size_t rowoff = (size_t)(orow + mi * 16 + r) * N;
#pragma unroll
      for (int ni = 0; ni < 4; ++ni)
        C[rowoff + ocol + ni * 16] = f2bf(acc[mi][ni][r]);
    }
}

// ---------------- GEMM2: C[M,N] fp32 = A[M,K] @ Bt[N,K]^T + bias ----------------
// 256x256 tile, BK=32, 512 threads (8 waves, 2Mx4N, wave-tile 128x64 = 8x4 of
// 16x16x32, one K-slice per tile). LDS 64 KiB -> 2 blocks/CU (was BK=64 /
// 128 KiB / 1 block/CU: every barrier idled the CU; co-resident block now
// fills the gaps). Counted-vmcnt double buffer: 4 loads/tile/thread,
// steady-state vmcnt(4), vmcnt(0) only at tail. XOR slot-swizzle for 4-slot
// rows: phys slot = quad ^ ((row>>1)&3) (spreads 16 frag-rows across all 8
// bank-groups -> 2-way = free); staging inverse on the global source:
// ssl = (lane&3) ^ ((lane>>3)&3) (wave/j-independent), LDS dest linear.
__global__ __launch_bounds__(512, 4)
void gemm2_kernel(const unsigned short* __restrict__ A,
                  const unsigned short* __restrict__ Bt,
                  float* __restrict__ C, const float* __restrict__ bias,
                  int N, int K, int GX) {
  __shared__ unsigned short sA[2][256 * 32];   // 32 KiB
  __shared__ unsigned short sB[2][256 * 32];   // 32 KiB

  const int tid  = threadIdx.x;
  const int lane = tid & 63;
  const int wave = tid >> 6;
  const int wm = (wave >> 2) * 128;            // 2 wave rows
  const int wn = (wave & 3) * 64;              // 4 wave cols

  unsigned bid  = blockIdx.x;
  unsigned bw   = 8u * GX;
  unsigned band = bid / bw, rem = bid % bw;
  unsigned by   = band * 8 + (rem & 7u);
  unsigned bx   = rem >> 3;
  const int row0 = by * 256, col0 = bx * 256;

  floatx4 acc[8][4];
#pragma unroll
  for (int i = 0; i < 8; ++i)
#pragma unroll
    for (int j = 0; j < 4; ++j) acc[i][j] = (floatx4){0.f, 0.f, 0.f, 0.f};

  // Staging: LDS dest linear (row = j*128 + wave*16 + lane/4, phys slot lane&3);
  // global source embeds inverse swizzle: slot = (lane&3) ^ ((row>>1)&3),
  // which reduces to (lane&3) ^ ((lane>>3)&3) (wave*16, j*128 are 0 mod 8).
  const int srow = wave * 16 + (lane >> 2);    // [0,128)
  const int ssl  = (lane & 3) ^ ((lane >> 3) & 3);
  const unsigned short* Ag = A  + (size_t)(row0 + srow) * K + ssl * 8;
  const unsigned short* Bg = Bt + (size_t)(col0 + srow) * K + ssl * 8;
  const int ldsw = (wave * 16) * 32;           // wave-uniform ushort offset

  // Fragment reads: phys 16B slot = quad ^ ((row>>1)&3); row = base16 + mrow
  // -> (row>>1)&3 == (mrow>>1)&3 (base16>>1 is 0 mod 8).
  const int mrow = lane & 15, quad = lane >> 4;
  const int pko  = (quad ^ ((mrow >> 1) & 3)) << 3;   // ushort offset

  const int NKT = K >> 5;                      // 32 for K=1024

  // 4 global_load_lds per K-tile per thread (2 A + 2 B), 128 rows per j-step.
#define STAGE_G2(KOFF, BUF)                                                    \
  {                                                                            \
    const unsigned short* As_ = Ag + (KOFF);                                   \
    const unsigned short* Bs_ = Bg + (KOFF);                                   \
    unsigned short* dA_ = &sA[(BUF)][0] + ldsw;                                \
    unsigned short* dB_ = &sB[(BUF)][0] + ldsw;                                \
    _Pragma("unroll")                                                          \
    for (int j_ = 0; j_ < 2; ++j_) {                                           \
      __builtin_amdgcn_global_load_lds((gptr_t)(As_ + (size_t)j_ * 128 * K),   \
                                       (lptr_t)(dA_ + j_ * 4096), 16, 0, 0);   \
      __builtin_amdgcn_global_load_lds((gptr_t)(Bs_ + (size_t)j_ * 128 * K),   \
                                       (lptr_t)(dB_ + j_ * 4096), 16, 0, 0);   \
    }                                                                          \
  }

  // Prologue: T0 -> buf0, T1 -> buf1; wait T0 landed (T1's 4 stay in flight).
  STAGE_G2(0, 0);
  STAGE_G2(32, 1);
  asm volatile("s_waitcnt vmcnt(4)" ::: "memory");
  __builtin_amdgcn_s_barrier();

  int cur = 0;
  for (int kt = 0; kt < NKT; ++kt) {
    const unsigned short* bA = &sA[cur][0];
    const unsigned short* bB = &sB[cur][0];
    bf16x8 bfr[4], af[8];
#pragma unroll
    for (int ni = 0; ni < 4; ++ni)
      bfr[ni] = __builtin_bit_cast(bf16x8,
                  *(const short8*)(bB + (wn + ni * 16 + mrow) * 32 + pko));
#pragma unroll
    for (int mi = 0; mi < 8; ++mi)
      af[mi] = __builtin_bit_cast(bf16x8,
                  *(const short8*)(bA + (wm + mi * 16 + mrow) * 32 + pko));
    __builtin_amdgcn_s_setprio(1);
#pragma unroll
    for (int mi = 0; mi < 8; ++mi)
#pragma unroll
      for (int ni = 0; ni < 4; ++ni)
        acc[mi][ni] = __builtin_amdgcn_mfma_f32_16x16x32_bf16(af[mi], bfr[ni],
                                                              acc[mi][ni], 0, 0, 0);
    __builtin_amdgcn_s_setprio(0);
    // All reads of buf[cur] complete -> barrier -> safe to restage buf[cur].
    asm volatile("s_waitcnt lgkmcnt(0)" ::: "memory");
    __builtin_amdgcn_sched_barrier(0);
    __builtin_amdgcn_s_barrier();
    __builtin_amdgcn_sched_barrier(0);
    if (kt + 2 < NKT) {
      STAGE_G2((kt + 2) * 32, cur);
      // wait for T(kt+1)'s 4 loads; T(kt+2)'s 4 remain in flight
      asm volatile("s_waitcnt vmcnt(4)" ::: "memory");
      __builtin_amdgcn_s_barrier();
    } else if (kt + 1 < NKT) {
      asm volatile("s_waitcnt vmcnt(0)" ::: "memory");
      __builtin_amdgcn_s_barrier();
    }
    cur ^= 1;
  }
#undef STAGE_G2

  const int orow = row0 + wm + quad * 4;
  const int ocol = col0 + wn + mrow;
  float bv[4];
#pragma unroll
  for (int ni = 0; ni < 4; ++ni) bv[ni] = bias[ocol + ni * 16];
#pragma unroll
  for (int mi = 0; mi < 8; ++mi)
#pragma unroll
    for (int r = 0; r < 4; ++r) {
      size_t rowoff = (size_t)(orow + mi * 16 + r) * N;
#pragma unroll
      for (int ni = 0; ni < 4; ++ni)
        C[rowoff + ocol + ni * 16] = acc[mi][ni][r] + bv[ni];
    }
}

extern "C" void kernel_launch(void* const* d_in, const int* in_sizes, int n_in,
                              void* d_out, int out_size, void* d_ws, size_t ws_size,
                              hipStream_t stream) {
  const float* x    = (const float*)d_in[0];  // [B*T, OUT_H]
  const float* U    = (const float*)d_in[1];  // [IN_H, RANK]
  const float* S    = (const float*)d_in[2];  // [RANK]
  const float* V    = (const float*)d_in[3];  // [OUT_H, RANK]
  const float* bias = (const float*)d_in[4];  // [IN_H]

  const int RANK = in_sizes[2];               // 1024
  const int INH  = in_sizes[4];               // 4096
  const int OUTH = in_sizes[3] / RANK;        // 4096
  const int M    = in_sizes[0] / OUTH;        // 8192

  unsigned short* Xb = (unsigned short*)d_ws;
  unsigned short* Vt = Xb + (size_t)M * OUTH;
  unsigned short* Ub = Vt + (size_t)RANK * OUTH;
  unsigned short* Yb = Ub + (size_t)INH * RANK;

  const int castBlocks = (int)(((size_t)M * OUTH) / 2048);
  const int transGX    = RANK / 32;
  const int transTotal = transGX * (OUTH / 32);
  const int prepUBlk   = (int)(((size_t)INH * RANK) / 1024);
  prep_fused<<<castBlocks + transTotal + prepUBlk, 256, 0, stream>>>(
      x, V, U, S, Xb, Vt, Ub, castBlocks, transTotal, transGX, OUTH, RANK,
      (unsigned)(RANK - 1));

  // GEMM1: grid = (M/128)*(RANK/128) = 64*8 = 512, GX=8
  gemm1_kernel<<<(M / 128) * (RANK / 128), 256, 0, stream>>>(
      Xb, Vt, Yb, RANK, OUTH, RANK / 128);

  // GEMM2: 256x256 tiles -> grid = (M/256)*(INH/256) = 32*16 = 512, GX=16
  gemm2_kernel<<<(M / 256) * (INH / 256), 512, 0, stream>>>(
      Yb, Ub, (float*)d_out, bias, INH, RANK, INH / 256);
}

// Round 6
// 387.125 us; speedup vs baseline: 2.5606x; 2.5606x over previous
//
#include <hip/hip_runtime.h>
#include <stdint.h>

typedef __attribute__((ext_vector_type(4))) float  floatx4;
typedef __attribute__((ext_vector_type(8))) short  short8;
typedef __attribute__((ext_vector_type(8))) __bf16 bf16x8;

__device__ __forceinline__ unsigned short f2bf(float f) {
  unsigned int u = __builtin_bit_cast(unsigned int, f);
  u += 0x7fffu + ((u >> 16) & 1u);   // round-to-nearest-even
  return (unsigned short)(u >> 16);
}

typedef const __attribute__((address_space(1))) void* gptr_t;
typedef __attribute__((address_space(3))) void*       lptr_t;

// ---------------- fused prep: cast_x | transpose_v | prep_u ----------------
__global__ __launch_bounds__(256) void prep_fused(
    const float* __restrict__ X, const float* __restrict__ V,
    const float* __restrict__ U, const float* __restrict__ S,
    unsigned short* __restrict__ Xb, unsigned short* __restrict__ Vt,
    unsigned short* __restrict__ Ub,
    int castBlocks, int transTotal, int transGX, int vrows, int vcols,
    unsigned int rankMask) {
  __shared__ float tile[32][33];
  int bid = blockIdx.x;
  int tid = threadIdx.x;
  if (bid < castBlocks) {
    size_t i = ((size_t)bid * 256 + tid) * 8;
    const floatx4* p = (const floatx4*)(X + i);
    floatx4 a = p[0], b = p[1];
    union { unsigned short us[8]; short8 v; } o;
    o.us[0] = f2bf(a[0]); o.us[1] = f2bf(a[1]); o.us[2] = f2bf(a[2]); o.us[3] = f2bf(a[3]);
    o.us[4] = f2bf(b[0]); o.us[5] = f2bf(b[1]); o.us[6] = f2bf(b[2]); o.us[7] = f2bf(b[3]);
    *(short8*)(Xb + i) = o.v;
  } else if (bid < castBlocks + transTotal) {
    int b  = bid - castBlocks;
    int bx = (b % transGX) * 32;     // rank dim
    int by = (b / transGX) * 32;     // out_h dim
    int tx = tid & 31;
    int ty = tid >> 5;
    for (int i = ty; i < 32; i += 8)
      tile[i][tx] = V[(size_t)(by + i) * vcols + bx + tx];
    __syncthreads();
    // Vectorized store: one 8B (4x bf16) store per thread.
    // Vt[bx+i][by+c] = tile[c][i]; thread (g=tid&7, i2=tid>>3) covers c=g*4..+3.
    {
      int g = tid & 7, i2 = tid >> 3;
      union { unsigned short us[4]; unsigned long long v; } w;
#pragma unroll
      for (int j = 0; j < 4; ++j) w.us[j] = f2bf(tile[g * 4 + j][i2]);
      *(unsigned long long*)(Vt + (size_t)(bx + i2) * vrows + by + g * 4) = w.v;
    }
  } else {
    int b = bid - castBlocks - transTotal;
    size_t i = ((size_t)b * 256 + tid) * 4;
    floatx4 u = *(const floatx4*)(U + i);
    floatx4 s = *(const floatx4*)(S + (i & (size_t)rankMask));
    union { unsigned short us[4]; unsigned long long v; } o;
    o.us[0] = f2bf(u[0] * s[0]); o.us[1] = f2bf(u[1] * s[1]);
    o.us[2] = f2bf(u[2] * s[2]); o.us[3] = f2bf(u[3] * s[3]);
    *(unsigned long long*)(Ub + i) = o.v;
  }
}

// ---------------- GEMM1: Yb[M,N] bf16 = A[M,K] @ Bt[N,K]^T ----------------
// BM=128, BN=128, BK=64, 256 threads (4 waves 2x2, wave-tile 64x64 = 4x4 of
// 16x16x32). Counted-vmcnt double buffer (8 loads/tile/thread, steady-state
// vmcnt(8), vmcnt(0) only at tail), XOR slot-swizzle, raw s_barrier, setprio.
// (Verified round-4: ~68 us.)
__global__ __launch_bounds__(256, 2)
void gemm1_kernel(const unsigned short* __restrict__ A,
                  const unsigned short* __restrict__ Bt,
                  unsigned short* __restrict__ C,
                  int N, int K, int GX) {
  __shared__ unsigned short sA[2][128 * 64];   // 16 KiB per buf
  __shared__ unsigned short sB[2][128 * 64];

  const int tid  = threadIdx.x;
  const int lane = tid & 63;
  const int wave = tid >> 6;
  const int wm = (wave >> 1) * 64;
  const int wn = (wave & 1) * 64;

  unsigned bid  = blockIdx.x;
  unsigned bw   = 8u * GX;
  unsigned band = bid / bw, rem = bid % bw;
  unsigned by   = band * 8 + (rem & 7u);
  unsigned bx   = rem >> 3;
  const int row0 = by * 128, col0 = bx * 128;

  floatx4 acc[4][4];
#pragma unroll
  for (int i = 0; i < 4; ++i)
#pragma unroll
    for (int j = 0; j < 4; ++j) acc[i][j] = (floatx4){0.f, 0.f, 0.f, 0.f};

  // Staging: LDS dest linear (row = j*32 + wave*8 + lane/8, slot lane&7);
  // global source embeds inverse swizzle: slot = (lane&7) ^ (row&7),
  // row&7 == lane>>3 (wave*8 and j*32 are 0 mod 8).
  const int srow = wave * 8 + (lane >> 3);     // [0,32)
  const int ssl  = (lane & 7) ^ (lane >> 3);
  const unsigned short* Ag = A  + (size_t)(row0 + srow) * K + ssl * 8;
  const unsigned short* Bg = Bt + (size_t)(col0 + srow) * K + ssl * 8;
  const int ldsw = (wave * 8) * 64;            // wave-uniform ushort offset

  // Fragment reads: phys 16B slot = (ks*4+quad) ^ (row&7), row&7 == mrow&7.
  const int mrow = lane & 15, quad = lane >> 4;
  const int sw   = mrow & 7;
  const int pko0 = ((quad    ) ^ sw) << 3;     // ks=0, ushort offset
  const int pko1 = ((quad + 4) ^ sw) << 3;     // ks=1

  const int NKT = K >> 6;                      // 64 for K=4096

  // 8 global_load_lds per K-tile per thread (4 A + 4 B), 32 rows per j-step.
#define STAGE_G1(KOFF, BUF)                                                    \
  {                                                                            \
    const unsigned short* As_ = Ag + (KOFF);                                   \
    const unsigned short* Bs_ = Bg + (KOFF);                                   \
    unsigned short* dA_ = &sA[(BUF)][0] + ldsw;                                \
    unsigned short* dB_ = &sB[(BUF)][0] + ldsw;                                \
    _Pragma("unroll")                                                          \
    for (int j_ = 0; j_ < 4; ++j_) {                                           \
      __builtin_amdgcn_global_load_lds((gptr_t)(As_ + (size_t)j_ * 32 * K),    \
                                       (lptr_t)(dA_ + j_ * 2048), 16, 0, 0);   \
      __builtin_amdgcn_global_load_lds((gptr_t)(Bs_ + (size_t)j_ * 32 * K),    \
                                       (lptr_t)(dB_ + j_ * 2048), 16, 0, 0);   \
    }                                                                          \
  }

  // Prologue: T0 -> buf0, T1 -> buf1; wait T0 landed (T1's 8 stay in flight).
  STAGE_G1(0, 0);
  STAGE_G1(64, 1);
  asm volatile("s_waitcnt vmcnt(8)" ::: "memory");
  __builtin_amdgcn_s_barrier();

  int cur = 0;
  for (int kt = 0; kt < NKT; ++kt) {
    const unsigned short* bA = &sA[cur][0];
    const unsigned short* bB = &sB[cur][0];
#pragma unroll
    for (int ks = 0; ks < 2; ++ks) {
      const int pko = ks ? pko1 : pko0;
      bf16x8 bfr[4], af[4];
#pragma unroll
      for (int ni = 0; ni < 4; ++ni)
        bfr[ni] = __builtin_bit_cast(bf16x8,
                    *(const short8*)(bB + (wn + ni * 16 + mrow) * 64 + pko));
#pragma unroll
      for (int mi = 0; mi < 4; ++mi)
        af[mi] = __builtin_bit_cast(bf16x8,
                    *(const short8*)(bA + (wm + mi * 16 + mrow) * 64 + pko));
      __builtin_amdgcn_s_setprio(1);
#pragma unroll
      for (int mi = 0; mi < 4; ++mi)
#pragma unroll
        for (int ni = 0; ni < 4; ++ni)
          acc[mi][ni] = __builtin_amdgcn_mfma_f32_16x16x32_bf16(af[mi], bfr[ni],
                                                                acc[mi][ni], 0, 0, 0);
      __builtin_amdgcn_s_setprio(0);
    }
    // All reads of buf[cur] complete -> barrier -> safe to restage buf[cur].
    asm volatile("s_waitcnt lgkmcnt(0)" ::: "memory");
    __builtin_amdgcn_sched_barrier(0);
    __builtin_amdgcn_s_barrier();
    __builtin_amdgcn_sched_barrier(0);
    if (kt + 2 < NKT) {
      STAGE_G1((kt + 2) * 64, cur);
      // wait for T(kt+1)'s 8 loads; T(kt+2)'s 8 remain in flight
      asm volatile("s_waitcnt vmcnt(8)" ::: "memory");
      __builtin_amdgcn_s_barrier();
    } else if (kt + 1 < NKT) {
      asm volatile("s_waitcnt vmcnt(0)" ::: "memory");
      __builtin_amdgcn_s_barrier();
    }
    cur ^= 1;
  }
#undef STAGE_G1

  const int orow = row0 + wm + quad * 4;
  const int ocol = col0 + wn + mrow;
#pragma unroll
  for (int mi = 0; mi < 4; ++mi)
#pragma unroll
    for (int r = 0; r < 4; ++r) {
      size_t rowoff = (size_t)(orow + mi * 16 + r) * N;
#pragma unroll
      for (int ni = 0; ni < 4; ++ni)
        C[rowoff + ocol + ni * 16] = f2bf(acc[mi][ni][r]);
    }
}

// ---------------- GEMM2: C[M,N] fp32 = A[M,K] @ Bt[N,K]^T + bias ----------------
// 256x128 tile, BK=32, 512 threads (8 waves, 4Mx2N, wave-tile 64x64 = 4x4 of
// 16x16x32). Wave-tile 64x64 -> acc = 64 floats/thread, so combined
// VGPR+AGPR ~120 fits the 128-reg budget of __launch_bounds__(512,4)
// WITHOUT spilling (round-5's 128x64 wave-tile needed 128 acc floats and
// spilled to scratch: 3.6 GB HBM traffic). LDS 48 KiB -> with the 128-reg
// fit, 2 blocks/CU (16 waves) co-resident to fill barrier gaps.
// Counted-vmcnt double buffer: 3 loads/tile/thread (2 A + 1 B), steady
// vmcnt(3), vmcnt(0) only at tail. BK=32 XOR slot-swizzle verified in r5
// (passed, SQ_LDS_BANK_CONFLICT = 0): phys slot = quad ^ ((row>>1)&3);
// staging inverse on global source ssl = (lane&3) ^ ((lane>>3)&3),
// LDS dest linear.
__global__ __launch_bounds__(512, 4)
void gemm2_kernel(const unsigned short* __restrict__ A,
                  const unsigned short* __restrict__ Bt,
                  float* __restrict__ C, const float* __restrict__ bias,
                  int N, int K, int GX) {
  __shared__ unsigned short sA[2][256 * 32];   // 16 KiB per buf
  __shared__ unsigned short sB[2][128 * 32];   // 8 KiB per buf

  const int tid  = threadIdx.x;
  const int lane = tid & 63;
  const int wave = tid >> 6;
  const int wm = (wave >> 1) * 64;             // 4 M-waves: 0,64,128,192
  const int wn = (wave & 1) * 64;              // 2 N-waves: 0,64

  unsigned bid  = blockIdx.x;
  unsigned bw   = 8u * GX;
  unsigned band = bid / bw, rem = bid % bw;
  unsigned by   = band * 8 + (rem & 7u);
  unsigned bx   = rem >> 3;
  const int row0 = by * 256, col0 = bx * 128;

  floatx4 acc[4][4];
#pragma unroll
  for (int i = 0; i < 4; ++i)
#pragma unroll
    for (int j = 0; j < 4; ++j) acc[i][j] = (floatx4){0.f, 0.f, 0.f, 0.f};

  // Staging: A rows j*128 + wave*16 + lane/4 (j=0,1), B rows wave*16 + lane/4;
  // phys slot lane&3 (LDS dest linear); global source slot embeds inverse
  // swizzle: ssl = (lane&3) ^ ((row>>1)&3) = (lane&3) ^ ((lane>>3)&3)
  // (wave*16>>1 and j*128>>1 are 0 mod 4).
  const int srow = wave * 16 + (lane >> 2);    // [0,128)
  const int ssl  = (lane & 3) ^ ((lane >> 3) & 3);
  const unsigned short* Ag = A  + (size_t)(row0 + srow) * K + ssl * 8;
  const unsigned short* Bg = Bt + (size_t)(col0 + srow) * K + ssl * 8;
  const int ldsw = (wave * 16) * 32;           // wave-uniform ushort offset

  // Fragment reads: phys 16B slot = quad ^ ((row>>1)&3); row = wm|wn + mi*16
  // + mrow -> (row>>1)&3 == (mrow>>1)&3 (wm,wn mult of 64; mi*16>>1 = mi*8).
  const int mrow = lane & 15, quad = lane >> 4;
  const int pko  = (quad ^ ((mrow >> 1) & 3)) << 3;   // ushort offset

  const int NKT = K >> 5;                      // 32 for K=1024

  // 3 global_load_lds per K-tile per thread (2 A + 1 B).
#define STAGE_G2(KOFF, BUF)                                                    \
  {                                                                            \
    const unsigned short* As_ = Ag + (KOFF);                                   \
    const unsigned short* Bs_ = Bg + (KOFF);                                   \
    unsigned short* dA_ = &sA[(BUF)][0] + ldsw;                                \
    unsigned short* dB_ = &sB[(BUF)][0] + ldsw;                                \
    __builtin_amdgcn_global_load_lds((gptr_t)(As_),                            \
                                     (lptr_t)(dA_), 16, 0, 0);                 \
    __builtin_amdgcn_global_load_lds((gptr_t)(As_ + (size_t)128 * K),          \
                                     (lptr_t)(dA_ + 4096), 16, 0, 0);          \
    __builtin_amdgcn_global_load_lds((gptr_t)(Bs_),                            \
                                     (lptr_t)(dB_), 16, 0, 0);                 \
  }

  // Prologue: T0 -> buf0, T1 -> buf1; wait T0 landed (T1's 3 stay in flight).
  STAGE_G2(0, 0);
  STAGE_G2(32, 1);
  asm volatile("s_waitcnt vmcnt(3)" ::: "memory");
  __builtin_amdgcn_s_barrier();

  int cur = 0;
  for (int kt = 0; kt < NKT; ++kt) {
    const unsigned short* bA = &sA[cur][0];
    const unsigned short* bB = &sB[cur][0];
    bf16x8 bfr[4], af[4];
#pragma unroll
    for (int ni = 0; ni < 4; ++ni)
      bfr[ni] = __builtin_bit_cast(bf16x8,
                  *(const short8*)(bB + (wn + ni * 16 + mrow) * 32 + pko));
#pragma unroll
    for (int mi = 0; mi < 4; ++mi)
      af[mi] = __builtin_bit_cast(bf16x8,
                  *(const short8*)(bA + (wm + mi * 16 + mrow) * 32 + pko));
    __builtin_amdgcn_s_setprio(1);
#pragma unroll
    for (int mi = 0; mi < 4; ++mi)
#pragma unroll
      for (int ni = 0; ni < 4; ++ni)
        acc[mi][ni] = __builtin_amdgcn_mfma_f32_16x16x32_bf16(af[mi], bfr[ni],
                                                              acc[mi][ni], 0, 0, 0);
    __builtin_amdgcn_s_setprio(0);
    // All reads of buf[cur] complete -> barrier -> safe to restage buf[cur].
    asm volatile("s_waitcnt lgkmcnt(0)" ::: "memory");
    __builtin_amdgcn_sched_barrier(0);
    __builtin_amdgcn_s_barrier();
    __builtin_amdgcn_sched_barrier(0);
    if (kt + 2 < NKT) {
      STAGE_G2((kt + 2) * 32, cur);
      // wait for T(kt+1)'s 3 loads; T(kt+2)'s 3 remain in flight
      asm volatile("s_waitcnt vmcnt(3)" ::: "memory");
      __builtin_amdgcn_s_barrier();
    } else if (kt + 1 < NKT) {
      asm volatile("s_waitcnt vmcnt(0)" ::: "memory");
      __builtin_amdgcn_s_barrier();
    }
    cur ^= 1;
  }
#undef STAGE_G2

  const int orow = row0 + wm + quad * 4;
  const int ocol = col0 + wn + mrow;
  float bv[4];
#pragma unroll
  for (int ni = 0; ni < 4; ++ni) bv[ni] = bias[ocol + ni * 16];
#pragma unroll
  for (int mi = 0; mi < 4; ++mi)
#pragma unroll
    for (int r = 0; r < 4; ++r) {
      size_t rowoff = (size_t)(orow + mi * 16 + r) * N;
#pragma unroll
      for (int ni = 0; ni < 4; ++ni)
        C[rowoff + ocol + ni * 16] = acc[mi][ni][r] + bv[ni];
    }
}

extern "C" void kernel_launch(void* const* d_in, const int* in_sizes, int n_in,
                              void* d_out, int out_size, void* d_ws, size_t ws_size,
                              hipStream_t stream) {
  const float* x    = (const float*)d_in[0];  // [B*T, OUT_H]
  const float* U    = (const float*)d_in[1];  // [IN_H, RANK]
  const float* S    = (const float*)d_in[2];  // [RANK]
  const float* V    = (const float*)d_in[3];  // [OUT_H, RANK]
  const float* bias = (const float*)d_in[4];  // [IN_H]

  const int RANK = in_sizes[2];               // 1024
  const int INH  = in_sizes[4];               // 4096
  const int OUTH = in_sizes[3] / RANK;        // 4096
  const int M    = in_sizes[0] / OUTH;        // 8192

  unsigned short* Xb = (unsigned short*)d_ws;
  unsigned short* Vt = Xb + (size_t)M * OUTH;
  unsigned short* Ub = Vt + (size_t)RANK * OUTH;
  unsigned short* Yb = Ub + (size_t)INH * RANK;

  const int castBlocks = (int)(((size_t)M * OUTH) / 2048);
  const int transGX    = RANK / 32;
  const int transTotal = transGX * (OUTH / 32);
  const int prepUBlk   = (int)(((size_t)INH * RANK) / 1024);
  prep_fused<<<castBlocks + transTotal + prepUBlk, 256, 0, stream>>>(
      x, V, U, S, Xb, Vt, Ub, castBlocks, transTotal, transGX, OUTH, RANK,
      (unsigned)(RANK - 1));

  // GEMM1: grid = (M/128)*(RANK/128) = 64*8 = 512, GX=8
  gemm1_kernel<<<(M / 128) * (RANK / 128), 256, 0, stream>>>(
      Xb, Vt, Yb, RANK, OUTH, RANK / 128);

  // GEMM2: 256x128 tiles -> grid = (M/256)*(INH/128) = 32*32 = 1024, GX=32
  gemm2_kernel<<<(M / 256) * (INH / 128), 512, 0, stream>>>(
      Yb, Ub, (float*)d_out, bias, INH, RANK, INH / 128);
}